// Round 8
// baseline (9237.809 us; speedup 1.0000x reference)
//
#include <hip/hip_runtime.h>
#include <hip/hip_bf16.h>
#include <stdint.h>

// GRU-style recurrence, B=64 S=512 D=768 H=1024.
//  prep:  cast x->bf16; Wcat_u bf16 [3072,1024]; WmT bf16; Wh bf16; ccat = W*_u@bm + b*;
//         pack recurrent weights (W*[:,1024:]) into per-block MFMA B-fragments (r,z,i).
//  fold:  Mcat[3072,768] = Wcat_u @ WmT^T           (NT bf16 MFMA GEMM)
//  big:   Gcat[32768,3072] = xbf @ Mcat^T + ccat    (NT bf16 MFMA GEMM, bf16 out)
//  h0:    hf[64,1024] = x[:,0,:] @ Whbf^T + bh
//  rec v8 = R7 skeleton + R5 tagged-word exchange:
//   - each communicated bf16 rides in a u32: payload<<16 | step_tag. Producer
//     fires 4 plain sc0sc1 dword stores (NO drain, NO flags). Consumer's poll
//     IS the fragment load: sweep 16x dwordx4 + vmcnt(0) + tag check -> one
//     die-level round trip per hop instead of three (drain+flag+load).
//   - 2-slot parity double buffer; slot-reuse causality proven via tag dataflow
//     (R5 passed). B2/B4 barriers only; wave0 Gcat prefetch double-buffered.

#define B_  64
#define S_  512
#define D_  768
#define H_  1024

typedef __attribute__((ext_vector_type(8))) short short8;
typedef __attribute__((ext_vector_type(4))) float f32x4;
typedef __attribute__((ext_vector_type(4))) unsigned int u32x4;

static __device__ __forceinline__ short f2bf(float f) {
  union { float f; uint32_t u; } v; v.f = f;
  uint32_t u = v.u;
  u += 0x7FFFu + ((u >> 16) & 1u);   // RNE
  return (short)(u >> 16);
}
static __device__ __forceinline__ float bf2f(short s) {
  union { uint32_t u; float f; } v; v.u = ((uint32_t)(uint16_t)s) << 16;
  return v.f;
}
static __device__ __forceinline__ void load_lds16(const void* g, void* l) {
  __builtin_amdgcn_global_load_lds((const __attribute__((address_space(1))) void*)g,
                                   (__attribute__((address_space(3))) void*)l, 16, 0, 0);
}

// ---- device-coherent tagged exchange ----
static __device__ __forceinline__ void store_tagged(uint32_t* p, uint32_t v) {
  asm volatile("global_store_dword %0, %1, off sc0 sc1" :: "v"(p), "v"(v) : "memory");
}
// poll one wave's 8 A-fragments (16 dwordx4 chunks) until every dword's low16==tag
static __device__ __forceinline__ void poll_frags(const uint32_t* rowbase, uint32_t tag,
                                                  u32x4* d) {
  for (;;) {
#pragma unroll
    for (int c = 0; c < 16; ++c) {
      const uint32_t* p = rowbase + ((c >> 1) << 5) + ((c & 1) << 2);
      asm volatile("global_load_dwordx4 %0, %1, off sc0 sc1" : "=v"(d[c]) : "v"(p));
    }
    asm volatile("s_waitcnt vmcnt(0)" ::: "memory");
    __builtin_amdgcn_sched_barrier(0);
    uint32_t bad = 0;
#pragma unroll
    for (int c = 0; c < 16; ++c)
#pragma unroll
      for (int e = 0; e < 4; ++e) bad |= (d[c][e] ^ tag);
    if (__all((int)((bad & 0xffffu) == 0u))) break;
  }
  __builtin_amdgcn_sched_barrier(0);
}
static __device__ __forceinline__ short8 frag_of(const u32x4 a, const u32x4 b) {
  short8 r;
  r[0] = (short)(a[0] >> 16); r[1] = (short)(a[1] >> 16);
  r[2] = (short)(a[2] >> 16); r[3] = (short)(a[3] >> 16);
  r[4] = (short)(b[0] >> 16); r[5] = (short)(b[1] >> 16);
  r[6] = (short)(b[2] >> 16); r[7] = (short)(b[3] >> 16);
  return r;
}

// ---------------- prep kernels ----------------

__global__ void cast_f32_bf16_kernel(const float* __restrict__ in, short* __restrict__ out, int n8) {
  int i = blockIdx.x * blockDim.x + threadIdx.x;
  int stride = gridDim.x * blockDim.x;
  for (; i < n8; i += stride) {
    const f32x4* p = (const f32x4*)(in + (size_t)i * 8);
    f32x4 a = p[0], b = p[1];
    short8 o;
    o[0] = f2bf(a[0]); o[1] = f2bf(a[1]); o[2] = f2bf(a[2]); o[3] = f2bf(a[3]);
    o[4] = f2bf(b[0]); o[5] = f2bf(b[1]); o[6] = f2bf(b[2]); o[7] = f2bf(b[3]);
    *(short8*)(out + (size_t)i * 8) = o;
  }
}

// h0 -> tagged words, tag 0, slot 0
__global__ void tag_h0_kernel(const float* __restrict__ hf, uint32_t* __restrict__ hx) {
  int i = blockIdx.x * blockDim.x + threadIdx.x;   // 65536
  hx[i] = ((uint32_t)(uint16_t)f2bf(hf[i]) << 16);
}

// Wcat_u bf16 [3072][1024]: rows 0..1023 = Wz[:, :1024], then Wr, then Wi
__global__ void build_wcat_kernel(const float* __restrict__ Wz, const float* __restrict__ Wr,
                                  const float* __restrict__ Wi, short* __restrict__ out) {
  int idx = blockIdx.x * blockDim.x + threadIdx.x;   // 3072*128
  int n = idx >> 7;
  int k8 = (idx & 127) << 3;
  const float* src;
  if (n < 1024)       src = Wz + ((size_t)n << 11);
  else if (n < 2048)  src = Wr + ((size_t)(n - 1024) << 11);
  else                src = Wi + ((size_t)(n - 2048) << 11);
  const f32x4* p = (const f32x4*)(src + k8);
  f32x4 a = p[0], b = p[1];
  short8 o;
  o[0] = f2bf(a[0]); o[1] = f2bf(a[1]); o[2] = f2bf(a[2]); o[3] = f2bf(a[3]);
  o[4] = f2bf(b[0]); o[5] = f2bf(b[1]); o[6] = f2bf(b[2]); o[7] = f2bf(b[3]);
  *(short8*)(out + ((size_t)n << 10) + k8) = o;
}

// WmT bf16 [768][1024], WmT[d][u] = Wm[u][d]
__global__ void transpose_cast_kernel(const float* __restrict__ in, short* __restrict__ out) {
  __shared__ float tile[32][33];
  int x = (blockIdx.x << 5) + threadIdx.x;    // d, grid.x = 24
  int y0 = (blockIdx.y << 5);                 // u, grid.y = 32
#pragma unroll
  for (int i = threadIdx.y; i < 32; i += 8)
    tile[i][threadIdx.x] = in[(size_t)(y0 + i) * 768 + x];
  __syncthreads();
  int ox = (blockIdx.y << 5) + threadIdx.x;
  int oy0 = (blockIdx.x << 5);
#pragma unroll
  for (int i = threadIdx.y; i < 32; i += 8)
    out[(size_t)(oy0 + i) * 1024 + ox] = f2bf(tile[threadIdx.x][i]);
}

// ccat[n] = sum_k W*[n_local, k<1024] * bm[k] + b*[n_local]
__global__ void ccat_kernel(const float* __restrict__ Wz, const float* __restrict__ Wr,
                            const float* __restrict__ Wi, const float* __restrict__ bm,
                            const float* __restrict__ bz, const float* __restrict__ br,
                            const float* __restrict__ bi, float* __restrict__ ccat) {
  int w = (blockIdx.x * blockDim.x + threadIdx.x) >> 6;
  int lane = threadIdx.x & 63;
  if (w >= 3072) return;
  const float* src; const float* bsrc; int ln;
  if (w < 1024)      { src = Wz + ((size_t)w << 11);          bsrc = bz; ln = w; }
  else if (w < 2048) { src = Wr + ((size_t)(w - 1024) << 11); bsrc = br; ln = w - 1024; }
  else               { src = Wi + ((size_t)(w - 2048) << 11); bsrc = bi; ln = w - 2048; }
  float acc = 0.f;
  for (int k = lane; k < 1024; k += 64) acc += src[k] * bm[k];
  for (int off = 32; off > 0; off >>= 1) acc += __shfl_down(acc, off, 64);
  if (lane == 0) ccat[w] = acc + bsrc[ln];
}

// pack recurrent weights: idx = (((m*64 + j)*4 + w)*8 + t8)*64 + lane, m: 0=r 1=z 2=i
// value = W_m[16j + (lane&15)][1024 + 256w + 32*t8 + 8*(lane>>4) + e]
__global__ void pack_w_kernel(const float* __restrict__ Wz, const float* __restrict__ Wr,
                              const float* __restrict__ Wi, short* __restrict__ out) {
  int idx = blockIdx.x * blockDim.x + threadIdx.x;   // 393216
  int lane = idx & 63;
  int t8 = (idx >> 6) & 7;
  int w = (idx >> 9) & 3;
  int j = (idx >> 11) & 63;
  int m = idx >> 17;
  int colv = (j << 4) + (lane & 15);
  int k = 1024 + (w << 8) + (t8 << 5) + ((lane >> 4) << 3);
  const float* W = (m == 0) ? Wr : (m == 1) ? Wz : Wi;
  const float* p = W + ((size_t)colv << 11) + k;
  short8 o;
#pragma unroll
  for (int e = 0; e < 8; ++e) o[e] = f2bf(p[e]);
  *(short8*)(out + ((size_t)idx << 3)) = o;
}

// ---------------- NT bf16 MFMA GEMM: C[M,N] = A[M,K] @ Bm[N,K]^T (+bias[col]) ----------------

template<bool OUT_F32>
__launch_bounds__(256, 2)
__global__ void gemm_nt_kernel(const short* __restrict__ A, long lda,
                               const short* __restrict__ Bm,
                               void* __restrict__ Cv, int ldc,
                               const float* __restrict__ bias,
                               int M, int N, int K) {
  __shared__ short ldsA[128 * 64];
  __shared__ short ldsB[128 * 64];
  const int tile_m = blockIdx.x << 7;
  const int tile_n = blockIdx.y << 7;
  const int tid = threadIdx.x;
  const int wave = tid >> 6;
  const int lane = tid & 63;
  const int wm = wave & 1;
  const int wn = wave >> 1;
  const int lrow = lane & 15;
  const int lgrp = lane >> 4;

  f32x4 acc[4][4];
#pragma unroll
  for (int a = 0; a < 4; ++a)
#pragma unroll
    for (int b = 0; b < 4; ++b) acc[a][b] = (f32x4){0.f, 0.f, 0.f, 0.f};

  for (int kt = 0; kt < K; kt += 64) {
    __syncthreads();
#pragma unroll
    for (int c = 0; c < 4; ++c) {
      int o = ((wave * 4 + c) << 10) + (lane << 4);
      int row = o >> 7;
      int cb = (o & 127) ^ ((row & 7) << 4);   // pre-swizzled source (rule 21)
      int grow = tile_m + row; if (grow >= M) grow = M - 1;
      load_lds16(A + (size_t)grow * lda + kt + (cb >> 1),
                 (char*)ldsA + ((wave * 4 + c) << 10));
      int gcol = tile_n + row;
      load_lds16(Bm + (size_t)gcol * K + kt + (cb >> 1),
                 (char*)ldsB + ((wave * 4 + c) << 10));
    }
    __syncthreads();
#pragma unroll
    for (int kk = 0; kk < 2; ++kk) {
      short8 af[4], bfr[4];
      int kb = (kk << 6) + (lgrp << 4);
#pragma unroll
      for (int a = 0; a < 4; ++a) {
        int r = (wm << 6) + (a << 4) + lrow;
        af[a] = *(const short8*)((const char*)ldsA + (r << 7) + (kb ^ ((r & 7) << 4)));
        int rn = (wn << 6) + (a << 4) + lrow;
        bfr[a] = *(const short8*)((const char*)ldsB + (rn << 7) + (kb ^ ((rn & 7) << 4)));
      }
#pragma unroll
      for (int a = 0; a < 4; ++a)
#pragma unroll
        for (int b = 0; b < 4; ++b)
          acc[a][b] = __builtin_amdgcn_mfma_f32_16x16x32_bf16(af[a], bfr[b], acc[a][b], 0, 0, 0);
    }
  }
#pragma unroll
  for (int a = 0; a < 4; ++a)
#pragma unroll
    for (int b = 0; b < 4; ++b)
#pragma unroll
      for (int q = 0; q < 4; ++q) {
        int r = tile_m + (wm << 6) + (a << 4) + lgrp * 4 + q;   // m89 C layout
        int cc = tile_n + (wn << 6) + (b << 4) + lrow;
        if (r < M) {
          float v = acc[a][b][q];
          if (bias) v += bias[cc];
          if (OUT_F32) ((float*)Cv)[(size_t)r * ldc + cc] = v;
          else         ((short*)Cv)[(size_t)r * ldc + cc] = f2bf(v);
        }
      }
}

// ---------------- persistent recurrence (tagged-word exchange, R7 structure) ----------------
// 256 blocks: g = blk>>6 (16 batch rows), j = blk&63 (cols 16j..16j+16 of ALL gates).
// hx/rhx: u32 [2 slots][64 rows][1024 cols]; word = bf16<<16 | tag.
//   h before step t: hx[t&1], tag t;  phase2 of t writes hx[(t+1)&1], tag t+1.
//   rh of step t:    rhx[t&1], tag t (phase1 of t writes it).
// Wave w polls only its own k-quarter fragments (poll IS the load). B2/B4 only.

__launch_bounds__(256, 1)
__global__ void recurrence_kernel(const short* __restrict__ pk,
                                  const short* __restrict__ Gcat,
                                  const float* __restrict__ hf,
                                  uint32_t* __restrict__ hx,
                                  uint32_t* __restrict__ rhx,
                                  float* __restrict__ out) {
  __shared__ float red[3][3][256];    // [matrix r/z/i][wave-1][lane*4+q]
  const int blk = blockIdx.x;
  const int g = blk >> 6;
  const int j = blk & 63;
  const int tid = threadIdx.x;
  const int wave = tid >> 6;
  const int lane = tid & 63;
  const int lrow = lane & 15;
  const int lgrp = lane >> 4;
  const int m0 = g << 4;

  // resident weights: per wave k-quarter, 8 frags per matrix
  short8 wr[8], wz[8], wi[8];
  {
    const short8* p8 = (const short8*)pk;
    size_t base = ((size_t)j * 4 + wave) * 8;
#pragma unroll
    for (int t8 = 0; t8 < 8; ++t8) wr[t8] = p8[(base + t8) * 64 + lane];
#pragma unroll
    for (int t8 = 0; t8 < 8; ++t8) wz[t8] = p8[((size_t)2048 + base + t8) * 64 + lane];
#pragma unroll
    for (int t8 = 0; t8 < 8; ++t8) wi[t8] = p8[((size_t)4096 + base + t8) * 64 + lane];
  }

  const int col = (j << 4) + lrow;                     // output column (0..1023)
  float hold[4];
  if (wave == 0) {
#pragma unroll
    for (int q = 0; q < 4; ++q)
      hold[q] = hf[((size_t)(m0 + lgrp * 4 + q) << 10) + col];
  }

  // per-lane A-fragment base: row = m0 + lrow, k-quarter = wave*256, sub-off = lgrp*8
  const size_t rowoff = (((size_t)(m0 + lrow)) << 10) + (wave << 8) + (lgrp << 3);

  // Gcat gate inputs, double-buffered one step ahead (wave0 only)
  float gz[4], gr[4], gi[4], gzn[4], grn[4], gin[4];
  if (wave == 0) {
#pragma unroll
    for (int q = 0; q < 4; ++q) {
      size_t rbase = ((size_t)(m0 + lgrp * 4 + q) * S_) * 3072;   // t = 0
      gz[q] = bf2f(Gcat[rbase + col]);
      gr[q] = bf2f(Gcat[rbase + 1024 + col]);
      gi[q] = bf2f(Gcat[rbase + 2048 + col]);
    }
  }

  for (int t = 0; t < S_; ++t) {
    const int slot_r = (t & 1) << 16;        // u32 offset of slot (64*1024)
    const int slot_w = ((t + 1) & 1) << 16;
    // ---- phase 1: poll own h fragments (tag t), r,z GEMMs ----
    u32x4 d[16];
    poll_frags(hx + slot_r + rowoff, (uint32_t)t, d);
    f32x4 accr = (f32x4){0.f,0.f,0.f,0.f}, accz = (f32x4){0.f,0.f,0.f,0.f};
#pragma unroll
    for (int t8 = 0; t8 < 8; ++t8) {
      short8 hfrag = frag_of(d[2 * t8], d[2 * t8 + 1]);
      accr = __builtin_amdgcn_mfma_f32_16x16x32_bf16(hfrag, wr[t8], accr, 0, 0, 0);
      accz = __builtin_amdgcn_mfma_f32_16x16x32_bf16(hfrag, wz[t8], accz, 0, 0, 0);
    }
    if (wave != 0) {
#pragma unroll
      for (int q = 0; q < 4; ++q) {
        red[0][wave - 1][lane * 4 + q] = accr[q];
        red[1][wave - 1][lane * 4 + q] = accz[q];
      }
    }
    __syncthreads();                                  // B2
    f32x4 zt = (f32x4){0.f,0.f,0.f,0.f};
    if (wave == 0) {
#pragma unroll
      for (int q = 0; q < 4; ++q) {
        int li = lane * 4 + q;
        float sr = accr[q] + red[0][0][li] + red[0][1][li] + red[0][2][li] + gr[q];
        float sz = accz[q] + red[1][0][li] + red[1][1][li] + red[1][2][li] + gz[q];
        sr = fminf(fmaxf(sr, -30.f), 30.f);
        sz = fminf(fmaxf(sz, -30.f), 30.f);
        float rv = 1.f / (1.f + __expf(-sr));
        zt[q] = 1.f / (1.f + __expf(-sz));
        uint32_t w32 = ((uint32_t)(uint16_t)f2bf(rv * hold[q]) << 16) | (uint32_t)t;
        store_tagged(rhx + slot_r + (((size_t)(m0 + lgrp * 4 + q)) << 10) + col, w32);
      }
      // prefetch next step's Gcat gate inputs (drains under phase-2 poll)
      int tn = (t < S_ - 1) ? t + 1 : t;
#pragma unroll
      for (int q = 0; q < 4; ++q) {
        size_t rbase = ((size_t)(m0 + lgrp * 4 + q) * S_ + tn) * 3072;
        gzn[q] = bf2f(Gcat[rbase + col]);
        grn[q] = bf2f(Gcat[rbase + 1024 + col]);
        gin[q] = bf2f(Gcat[rbase + 2048 + col]);
      }
    }
    // ---- phase 2: poll own rh fragments (tag t), i GEMM ----
    poll_frags(rhx + slot_r + rowoff, (uint32_t)t, d);
    f32x4 acci = (f32x4){0.f,0.f,0.f,0.f};
#pragma unroll
    for (int t8 = 0; t8 < 8; ++t8) {
      short8 rhfrag = frag_of(d[2 * t8], d[2 * t8 + 1]);
      acci = __builtin_amdgcn_mfma_f32_16x16x32_bf16(rhfrag, wi[t8], acci, 0, 0, 0);
    }
    if (wave != 0) {
#pragma unroll
      for (int q = 0; q < 4; ++q) red[2][wave - 1][lane * 4 + q] = acci[q];
    }
    __syncthreads();                                  // B4
    if (wave == 0) {
#pragma unroll
      for (int q = 0; q < 4; ++q) {
        int li = lane * 4 + q;
        float si = acci[q] + red[2][0][li] + red[2][1][li] + red[2][2][li] + gi[q];
        si = fminf(fmaxf(si, -30.f), 30.f);
        float e2 = __expf(2.f * si);
        float hp = (e2 - 1.f) / (e2 + 1.f);
        float hn = (1.f - zt[q]) * hold[q] + zt[q] * hp;
        hold[q] = hn;
        uint32_t w32 = ((uint32_t)(uint16_t)f2bf(hn) << 16) | (uint32_t)(t + 1);
        store_tagged(hx + slot_w + (((size_t)(m0 + lgrp * 4 + q)) << 10) + col, w32);
        if (t == S_ - 1) out[((size_t)(m0 + lgrp * 4 + q) << 10) + col] = hn;
        gz[q] = gzn[q]; gr[q] = grn[q]; gi[q] = gin[q];
      }
    }
    // no end-of-step barrier: waves self-gate on their own tags next step
  }
}

// ---------------- launch ----------------

extern "C" void kernel_launch(void* const* d_in, const int* in_sizes, int n_in,
                              void* d_out, int out_size, void* d_ws, size_t ws_size,
                              hipStream_t stream) {
  const float* x  = (const float*)d_in[0];
  const float* Wm = (const float*)d_in[1];
  const float* bm = (const float*)d_in[2];
  const float* Wh = (const float*)d_in[3];
  const float* bh = (const float*)d_in[4];
  const float* Wz = (const float*)d_in[5];
  const float* bz = (const float*)d_in[6];
  const float* Wr = (const float*)d_in[7];
  const float* br = (const float*)d_in[8];
  const float* Wi = (const float*)d_in[9];
  const float* bi = (const float*)d_in[10];

  char* ws = (char*)d_ws;
  size_t off = 0;
  auto alloc = [&](size_t bytes) -> void* {
    void* p = ws + off; off += (bytes + 255) & ~(size_t)255; return p;
  };
  short* xbf   = (short*)alloc((size_t)B_ * S_ * D_ * 2);
  short* Gcat  = (short*)alloc((size_t)B_ * S_ * 3072 * 2);
  short* Mcat  = (short*)alloc((size_t)3072 * 768 * 2);
  short* Wcat  = (short*)alloc((size_t)3072 * 1024 * 2);
  short* WmT   = (short*)alloc((size_t)768 * 1024 * 2);
  short* Whbf  = (short*)alloc((size_t)1024 * 768 * 2);
  short* pk    = (short*)alloc((size_t)3 * 1024 * 1024 * 2);   // packed r,z,i frags
  float* ccat  = (float*)alloc(3072 * 4);
  float* hf    = (float*)alloc(65536 * 4);
  uint32_t* hx  = (uint32_t*)alloc((size_t)2 * 65536 * 4);     // tagged h, 2 slots
  uint32_t* rhx = (uint32_t*)alloc((size_t)2 * 65536 * 4);     // tagged r*h, 2 slots
  if (off > ws_size) return;

  hipMemsetAsync(hx, 0xEE, (size_t)2 * 65536 * 4, stream);     // no tag collision
  hipMemsetAsync(rhx, 0xEE, (size_t)2 * 65536 * 4, stream);
  cast_f32_bf16_kernel<<<2048, 256, 0, stream>>>(x, xbf, (B_ * S_ * D_) / 8);
  cast_f32_bf16_kernel<<<384, 256, 0, stream>>>(Wh, Whbf, (1024 * 768) / 8);
  build_wcat_kernel<<<1536, 256, 0, stream>>>(Wz, Wr, Wi, Wcat);
  transpose_cast_kernel<<<dim3(24, 32), dim3(32, 8), 0, stream>>>(Wm, WmT);
  ccat_kernel<<<768, 256, 0, stream>>>(Wz, Wr, Wi, bm, bz, br, bi, ccat);
  pack_w_kernel<<<1536, 256, 0, stream>>>(Wz, Wr, Wi, pk);

  // Mcat[3072,768] = Wcat[3072,1024] @ WmT[768,1024]^T
  gemm_nt_kernel<false><<<dim3(24, 6), 256, 0, stream>>>(Wcat, 1024, WmT, Mcat, 768,
                                                         nullptr, 3072, 768, 1024);
  // Gcat[32768,3072] = xbf[32768,768] @ Mcat[3072,768]^T + ccat
  gemm_nt_kernel<false><<<dim3(256, 24), 256, 0, stream>>>(xbf, 768, Mcat, Gcat, 3072,
                                                           ccat, 32768, 3072, 768);
  // hf[64,1024] = x[:,0,:] @ Whbf[1024,768]^T + bh
  gemm_nt_kernel<true><<<dim3(1, 8), 256, 0, stream>>>(xbf, (long)S_ * D_, Whbf, hf, 1024,
                                                       bh, 64, 1024, 768);
  tag_h0_kernel<<<256, 256, 0, stream>>>(hf, hx);      // h0 -> slot 0, tag 0

  recurrence_kernel<<<256, 256, 0, stream>>>(pk, Gcat, hf, hx, rhx, (float*)d_out);
}

// Round 9
// 2948.008 us; speedup vs baseline: 3.1336x; 3.1336x over previous
//
#include <hip/hip_runtime.h>
#include <hip/hip_bf16.h>
#include <stdint.h>

// GRU-style recurrence, B=64 S=512 D=768 H=1024.
//  prep:  cast x->bf16; Wcat_u bf16 [3072,1024]; WmT bf16; Wh bf16; ccat = W*_u@bm + b*;
//         pack recurrent weights (W*[:,1024:]) into per-block MFMA B-fragments (r,z,i).
//  fold:  Mcat[3072,768] = Wcat_u @ WmT^T           (NT bf16 MFMA GEMM)
//  big:   Gcat[32768,3072] = xbf @ Mcat^T + ccat    (NT bf16 MFMA GEMM, bf16 out)
//  h0:    hf[64,1024] = x[:,0,:] @ Whbf^T + bh
//  rec v9 = R7 skeleton + L3-resident packed exchange:
//   - h/rh exchanged via PACKED blocks hp/rhp[(g*64+j)*256 + row16*16 + col16] bf16
//     (512B contiguous per producer). Consumer MFMA fragment = one 16B dwordx4.
//   - producer stores via global_atomic_swap_x2 (device-coherent, resolves in L3,
//     NO HBM write-through) -> release drain = L3 ack; consumer sc0sc1 loads hit
//     L3-dirty lines. One 8B atomic per lane (transposed epilogue via LDS).
//   - flags (64B-padded lines), per-wave sliced polls, Gcat prefetch: as R7.

#define B_  64
#define S_  512
#define D_  768
#define H_  1024

typedef __attribute__((ext_vector_type(8))) short short8;
typedef __attribute__((ext_vector_type(4))) float f32x4;
typedef __attribute__((ext_vector_type(4))) unsigned short u16x4;

static __device__ __forceinline__ short f2bf(float f) {
  union { float f; uint32_t u; } v; v.f = f;
  uint32_t u = v.u;
  u += 0x7FFFu + ((u >> 16) & 1u);   // RNE
  return (short)(u >> 16);
}
static __device__ __forceinline__ float bf2f(short s) {
  union { uint32_t u; float f; } v; v.u = ((uint32_t)(uint16_t)s) << 16;
  return v.f;
}
static __device__ __forceinline__ void load_lds16(const void* g, void* l) {
  __builtin_amdgcn_global_load_lds((const __attribute__((address_space(1))) void*)g,
                                   (__attribute__((address_space(3))) void*)l, 16, 0, 0);
}

// ---- exchange primitives ----
// consumer loads bypass L1/L2, read at the coherence point (L3-hit if dirty there)
static __device__ __forceinline__ short8 load_frag_sys(const short* p) {
  short8 v;
  asm volatile("global_load_dwordx4 %0, %1, off sc0 sc1" : "=v"(v) : "v"(p));
  return v;
}
// producer stores: device-scope atomics resolve in L3 (no HBM write-through, m20)
static __device__ __forceinline__ void atomic_store64(void* p, uint64_t v) {
  asm volatile("global_atomic_swap_x2 %0, %1, off" :: "v"(p), "v"(v) : "memory");
}
static __device__ __forceinline__ void atomic_store32(uint32_t* p, uint32_t v) {
  asm volatile("global_atomic_swap %0, %1, off" :: "v"(p), "v"(v) : "memory");
}
static __device__ __forceinline__ void wait_vm0() {
  asm volatile("s_waitcnt vmcnt(0)" ::: "memory");
  __builtin_amdgcn_sched_barrier(0);   // rule 18: keep consumers below the drain
}
// each WAVE polls the 16 line-padded flags of its k-quarter producers
static __device__ __forceinline__ void poll16(const uint32_t* base, uint32_t target) {
  const uint32_t* addr = base + ((threadIdx.x & 15) << 4);   // 64B-strided flags
  for (;;) {
    uint32_t v;
    asm volatile("global_load_dword %0, %1, off sc0 sc1\n\ts_waitcnt vmcnt(0)"
                 : "=v"(v) : "v"(addr) : "memory");
    if (__all((int)(v >= target))) break;
    __builtin_amdgcn_s_sleep(1);
  }
  __builtin_amdgcn_sched_barrier(0);
}

// ---------------- prep kernels ----------------

__global__ void cast_f32_bf16_kernel(const float* __restrict__ in, short* __restrict__ out, int n8) {
  int i = blockIdx.x * blockDim.x + threadIdx.x;
  int stride = gridDim.x * blockDim.x;
  for (; i < n8; i += stride) {
    const f32x4* p = (const f32x4*)(in + (size_t)i * 8);
    f32x4 a = p[0], b = p[1];
    short8 o;
    o[0] = f2bf(a[0]); o[1] = f2bf(a[1]); o[2] = f2bf(a[2]); o[3] = f2bf(a[3]);
    o[4] = f2bf(b[0]); o[5] = f2bf(b[1]); o[6] = f2bf(b[2]); o[7] = f2bf(b[3]);
    *(short8*)(out + (size_t)i * 8) = o;
  }
}

// h0 -> packed exchange layout hp[(g*64+j)*256 + row*16 + col] = h0[16g+row][16j+col]
__global__ void pack_h0_kernel(const float* __restrict__ hf, short* __restrict__ hp) {
  int i = blockIdx.x * blockDim.x + threadIdx.x;   // 65536
  int col = i & 15, row = (i >> 4) & 15, j = (i >> 8) & 63, g = i >> 14;
  hp[i] = f2bf(hf[(size_t)(16 * g + row) * 1024 + j * 16 + col]);
}

// Wcat_u bf16 [3072][1024]: rows 0..1023 = Wz[:, :1024], then Wr, then Wi
__global__ void build_wcat_kernel(const float* __restrict__ Wz, const float* __restrict__ Wr,
                                  const float* __restrict__ Wi, short* __restrict__ out) {
  int idx = blockIdx.x * blockDim.x + threadIdx.x;   // 3072*128
  int n = idx >> 7;
  int k8 = (idx & 127) << 3;
  const float* src;
  if (n < 1024)       src = Wz + ((size_t)n << 11);
  else if (n < 2048)  src = Wr + ((size_t)(n - 1024) << 11);
  else                src = Wi + ((size_t)(n - 2048) << 11);
  const f32x4* p = (const f32x4*)(src + k8);
  f32x4 a = p[0], b = p[1];
  short8 o;
  o[0] = f2bf(a[0]); o[1] = f2bf(a[1]); o[2] = f2bf(a[2]); o[3] = f2bf(a[3]);
  o[4] = f2bf(b[0]); o[5] = f2bf(b[1]); o[6] = f2bf(b[2]); o[7] = f2bf(b[3]);
  *(short8*)(out + ((size_t)n << 10) + k8) = o;
}

// WmT bf16 [768][1024], WmT[d][u] = Wm[u][d]
__global__ void transpose_cast_kernel(const float* __restrict__ in, short* __restrict__ out) {
  __shared__ float tile[32][33];
  int x = (blockIdx.x << 5) + threadIdx.x;    // d, grid.x = 24
  int y0 = (blockIdx.y << 5);                 // u, grid.y = 32
#pragma unroll
  for (int i = threadIdx.y; i < 32; i += 8)
    tile[i][threadIdx.x] = in[(size_t)(y0 + i) * 768 + x];
  __syncthreads();
  int ox = (blockIdx.y << 5) + threadIdx.x;
  int oy0 = (blockIdx.x << 5);
#pragma unroll
  for (int i = threadIdx.y; i < 32; i += 8)
    out[(size_t)(oy0 + i) * 1024 + ox] = f2bf(tile[threadIdx.x][i]);
}

// ccat[n] = sum_k W*[n_local, k<1024] * bm[k] + b*[n_local]
__global__ void ccat_kernel(const float* __restrict__ Wz, const float* __restrict__ Wr,
                            const float* __restrict__ Wi, const float* __restrict__ bm,
                            const float* __restrict__ bz, const float* __restrict__ br,
                            const float* __restrict__ bi, float* __restrict__ ccat) {
  int w = (blockIdx.x * blockDim.x + threadIdx.x) >> 6;
  int lane = threadIdx.x & 63;
  if (w >= 3072) return;
  const float* src; const float* bsrc; int ln;
  if (w < 1024)      { src = Wz + ((size_t)w << 11);          bsrc = bz; ln = w; }
  else if (w < 2048) { src = Wr + ((size_t)(w - 1024) << 11); bsrc = br; ln = w - 1024; }
  else               { src = Wi + ((size_t)(w - 2048) << 11); bsrc = bi; ln = w - 2048; }
  float acc = 0.f;
  for (int k = lane; k < 1024; k += 64) acc += src[k] * bm[k];
  for (int off = 32; off > 0; off >>= 1) acc += __shfl_down(acc, off, 64);
  if (lane == 0) ccat[w] = acc + bsrc[ln];
}

// pack recurrent weights: idx = (((m*64 + j)*4 + w)*8 + t8)*64 + lane, m: 0=r 1=z 2=i
// value = W_m[16j + (lane&15)][1024 + 256w + 32*t8 + 8*(lane>>4) + e]
__global__ void pack_w_kernel(const float* __restrict__ Wz, const float* __restrict__ Wr,
                              const float* __restrict__ Wi, short* __restrict__ out) {
  int idx = blockIdx.x * blockDim.x + threadIdx.x;   // 393216
  int lane = idx & 63;
  int t8 = (idx >> 6) & 7;
  int w = (idx >> 9) & 3;
  int j = (idx >> 11) & 63;
  int m = idx >> 17;
  int colv = (j << 4) + (lane & 15);
  int k = 1024 + (w << 8) + (t8 << 5) + ((lane >> 4) << 3);
  const float* W = (m == 0) ? Wr : (m == 1) ? Wz : Wi;
  const float* p = W + ((size_t)colv << 11) + k;
  short8 o;
#pragma unroll
  for (int e = 0; e < 8; ++e) o[e] = f2bf(p[e]);
  *(short8*)(out + ((size_t)idx << 3)) = o;
}

// ---------------- NT bf16 MFMA GEMM: C[M,N] = A[M,K] @ Bm[N,K]^T (+bias[col]) ----------------

template<bool OUT_F32>
__launch_bounds__(256, 2)
__global__ void gemm_nt_kernel(const short* __restrict__ A, long lda,
                               const short* __restrict__ Bm,
                               void* __restrict__ Cv, int ldc,
                               const float* __restrict__ bias,
                               int M, int N, int K) {
  __shared__ short ldsA[128 * 64];
  __shared__ short ldsB[128 * 64];
  const int tile_m = blockIdx.x << 7;
  const int tile_n = blockIdx.y << 7;
  const int tid = threadIdx.x;
  const int wave = tid >> 6;
  const int lane = tid & 63;
  const int wm = wave & 1;
  const int wn = wave >> 1;
  const int lrow = lane & 15;
  const int lgrp = lane >> 4;

  f32x4 acc[4][4];
#pragma unroll
  for (int a = 0; a < 4; ++a)
#pragma unroll
    for (int b = 0; b < 4; ++b) acc[a][b] = (f32x4){0.f, 0.f, 0.f, 0.f};

  for (int kt = 0; kt < K; kt += 64) {
    __syncthreads();
#pragma unroll
    for (int c = 0; c < 4; ++c) {
      int o = ((wave * 4 + c) << 10) + (lane << 4);
      int row = o >> 7;
      int cb = (o & 127) ^ ((row & 7) << 4);   // pre-swizzled source (rule 21)
      int grow = tile_m + row; if (grow >= M) grow = M - 1;
      load_lds16(A + (size_t)grow * lda + kt + (cb >> 1),
                 (char*)ldsA + ((wave * 4 + c) << 10));
      int gcol = tile_n + row;
      load_lds16(Bm + (size_t)gcol * K + kt + (cb >> 1),
                 (char*)ldsB + ((wave * 4 + c) << 10));
    }
    __syncthreads();
#pragma unroll
    for (int kk = 0; kk < 2; ++kk) {
      short8 af[4], bfr[4];
      int kb = (kk << 6) + (lgrp << 4);
#pragma unroll
      for (int a = 0; a < 4; ++a) {
        int r = (wm << 6) + (a << 4) + lrow;
        af[a] = *(const short8*)((const char*)ldsA + (r << 7) + (kb ^ ((r & 7) << 4)));
        int rn = (wn << 6) + (a << 4) + lrow;
        bfr[a] = *(const short8*)((const char*)ldsB + (rn << 7) + (kb ^ ((rn & 7) << 4)));
      }
#pragma unroll
      for (int a = 0; a < 4; ++a)
#pragma unroll
        for (int b = 0; b < 4; ++b)
          acc[a][b] = __builtin_amdgcn_mfma_f32_16x16x32_bf16(af[a], bfr[b], acc[a][b], 0, 0, 0);
    }
  }
#pragma unroll
  for (int a = 0; a < 4; ++a)
#pragma unroll
    for (int b = 0; b < 4; ++b)
#pragma unroll
      for (int q = 0; q < 4; ++q) {
        int r = tile_m + (wm << 6) + (a << 4) + lgrp * 4 + q;   // m89 C layout
        int cc = tile_n + (wn << 6) + (b << 4) + lrow;
        if (r < M) {
          float v = acc[a][b][q];
          if (bias) v += bias[cc];
          if (OUT_F32) ((float*)Cv)[(size_t)r * ldc + cc] = v;
          else         ((short*)Cv)[(size_t)r * ldc + cc] = f2bf(v);
        }
      }
}

// ---------------- persistent recurrence (packed L3-resident exchange) ----------------
// 256 blocks: g = blk>>6 (16 batch rows), j = blk&63 (cols 16j..16j+16 of ALL gates).
// hp/rhp: bf16 [(g*64+j)][row16][col16], 512B/producer. Single-buffered (WAR closure
// via B2/B4 + flags, as R7). flags: per group [j*16]=flagA, [1024+j*16]=flagB.
// Consumer wave w, frag t8: producer j0=16w+2*t8+(lgrp>>1), 16B dwordx4 at
//   (g*64+j0)*512 + lrow*32 + (lgrp&1)*16 bytes.
// Producer (wave0, transposed epilogue): lane l -> row16=l>>2, cols (l&3)*4..+3,
//   one atomic_swap_x2 (8B) at (g*64+j)*512 + row16*32 + (l&3)*8.

__launch_bounds__(256, 1)
__global__ void recurrence_kernel(const short* __restrict__ pk,
                                  const short* __restrict__ Gcat,
                                  const float* __restrict__ hf,
                                  short* __restrict__ hp,
                                  short* __restrict__ rhp,
                                  uint32_t* __restrict__ flags,
                                  float* __restrict__ out) {
  __shared__ float red[3][4][320];   // [matrix r/z/i][wave][lane*5+q] (stride 5: 2-way max)
  const int blk = blockIdx.x;
  const int g = blk >> 6;
  const int j = blk & 63;
  const int tid = threadIdx.x;
  const int wave = tid >> 6;
  const int lane = tid & 63;
  const int lrow = lane & 15;
  const int lgrp = lane >> 4;
  const int m0 = g << 4;

  // resident weights: per wave k-quarter, 8 frags per matrix
  short8 wr[8], wz[8], wi[8];
  {
    const short8* p8 = (const short8*)pk;
    size_t base = ((size_t)j * 4 + wave) * 8;
#pragma unroll
    for (int t8 = 0; t8 < 8; ++t8) wr[t8] = p8[(base + t8) * 64 + lane];
#pragma unroll
    for (int t8 = 0; t8 < 8; ++t8) wz[t8] = p8[((size_t)2048 + base + t8) * 64 + lane];
#pragma unroll
    for (int t8 = 0; t8 < 8; ++t8) wi[t8] = p8[((size_t)4096 + base + t8) * 64 + lane];
  }

  uint32_t* fgrp = flags + (g << 11);           // flagA at +0, flagB at +1024 (dwords)

  // transposed epilogue assignment (wave0): row16 = lane>>2, cols c4..c4+3
  const int row16 = lane >> 2;
  const int c4 = (lane & 3) << 2;
  float hold[4];
  float zv[4];
  if (wave == 0) {
#pragma unroll
    for (int c = 0; c < 4; ++c)
      hold[c] = hf[((size_t)(m0 + row16) << 10) + (j << 4) + c4 + c];
  }

  // consumer fragment bases (bf16 elements): per t8 add 2 producers = 512 elems
  const size_t cbase = ((size_t)(g * 64) << 8);
  const int coff = ((16 * wave + (lgrp >> 1)) << 8) + (lrow << 4) + ((lgrp & 1) << 3);

  // producer store byte address (wave0)
  short* const prodRh = rhp + ((size_t)(g * 64 + j) << 8) + (row16 << 4) + c4;
  short* const prodH  = hp  + ((size_t)(g * 64 + j) << 8) + (row16 << 4) + c4;

  // Gcat gate inputs (transposed assignment), double-buffered one step ahead
  float gz[4], gr[4], gi[4], gzn[4], grn[4], gin[4];
  const unsigned short* GcatU = (const unsigned short*)Gcat;
  if (wave == 0) {
    size_t rbase = ((size_t)(m0 + row16) * S_) * 3072 + (j << 4) + c4;   // t = 0
    u16x4 vz = *(const u16x4*)(GcatU + rbase);
    u16x4 vr = *(const u16x4*)(GcatU + rbase + 1024);
    u16x4 vi = *(const u16x4*)(GcatU + rbase + 2048);
#pragma unroll
    for (int c = 0; c < 4; ++c) {
      gz[c] = bf2f((short)vz[c]); gr[c] = bf2f((short)vr[c]); gi[c] = bf2f((short)vi[c]);
    }
  }

  for (int t = 0; t < S_; ++t) {
    // ---- phase 1: self-gated on this wave's 16 h-producers ----
    if (t > 0) poll16(fgrp + 1024 + (wave << 8), (uint32_t)t);
    short8 hfrag[8];
#pragma unroll
    for (int t8 = 0; t8 < 8; ++t8)
      hfrag[t8] = load_frag_sys(hp + cbase + coff + (t8 << 9));
    wait_vm0();
    f32x4 accr = (f32x4){0.f,0.f,0.f,0.f}, accz = (f32x4){0.f,0.f,0.f,0.f};
#pragma unroll
    for (int t8 = 0; t8 < 8; ++t8) {
      accr = __builtin_amdgcn_mfma_f32_16x16x32_bf16(hfrag[t8], wr[t8], accr, 0, 0, 0);
      accz = __builtin_amdgcn_mfma_f32_16x16x32_bf16(hfrag[t8], wz[t8], accz, 0, 0, 0);
    }
#pragma unroll
    for (int q = 0; q < 4; ++q) {
      red[0][wave][lane * 5 + q] = accr[q];
      red[1][wave][lane * 5 + q] = accz[q];
    }
    __syncthreads();                                  // B2 (joins all sliced polls)
    if (wave == 0) {
      uint32_t packed[2] = {0u, 0u};
#pragma unroll
      for (int c = 0; c < 4; ++c) {
        int li = (((row16 >> 2) << 4) + c4 + c) * 5 + (row16 & 3);
        float sr = red[0][0][li] + red[0][1][li] + red[0][2][li] + red[0][3][li] + gr[c];
        float sz = red[1][0][li] + red[1][1][li] + red[1][2][li] + red[1][3][li] + gz[c];
        sr = fminf(fmaxf(sr, -30.f), 30.f);
        sz = fminf(fmaxf(sz, -30.f), 30.f);
        float rv = 1.f / (1.f + __expf(-sr));
        zv[c] = 1.f / (1.f + __expf(-sz));
        packed[c >> 1] |= ((uint32_t)(uint16_t)f2bf(rv * hold[c])) << ((c & 1) * 16);
      }
      atomic_store64(prodRh, ((uint64_t)packed[1] << 32) | packed[0]);
      wait_vm0();                                     // release: atomic acked at L3
      if (lane == 0) atomic_store32(fgrp + (j << 4), (uint32_t)(t + 1));
      // prefetch next step's Gcat gate inputs (drains under phase-2 poll/load)
      int tn = (t < S_ - 1) ? t + 1 : t;
      size_t rbase = ((size_t)(m0 + row16) * S_ + tn) * 3072 + (j << 4) + c4;
      u16x4 vz = *(const u16x4*)(GcatU + rbase);
      u16x4 vr = *(const u16x4*)(GcatU + rbase + 1024);
      u16x4 vi = *(const u16x4*)(GcatU + rbase + 2048);
#pragma unroll
      for (int c = 0; c < 4; ++c) {
        gzn[c] = bf2f((short)vz[c]); grn[c] = bf2f((short)vr[c]); gin[c] = bf2f((short)vi[c]);
      }
    }
    // ---- phase 2: self-gated on this wave's 16 rh-producers ----
    poll16(fgrp + (wave << 8), (uint32_t)(t + 1));
    short8 rhfrag[8];
#pragma unroll
    for (int t8 = 0; t8 < 8; ++t8)
      rhfrag[t8] = load_frag_sys(rhp + cbase + coff + (t8 << 9));
    wait_vm0();
    f32x4 acci = (f32x4){0.f,0.f,0.f,0.f};
#pragma unroll
    for (int t8 = 0; t8 < 8; ++t8)
      acci = __builtin_amdgcn_mfma_f32_16x16x32_bf16(rhfrag[t8], wi[t8], acci, 0, 0, 0);
#pragma unroll
    for (int q = 0; q < 4; ++q) red[2][wave][lane * 5 + q] = acci[q];
    __syncthreads();                                  // B4 (joins all sliced polls)
    if (wave == 0) {
      uint32_t packed[2] = {0u, 0u};
      float hn4[4];
#pragma unroll
      for (int c = 0; c < 4; ++c) {
        int li = (((row16 >> 2) << 4) + c4 + c) * 5 + (row16 & 3);
        float si = red[2][0][li] + red[2][1][li] + red[2][2][li] + red[2][3][li] + gi[c];
        si = fminf(fmaxf(si, -30.f), 30.f);
        float e2 = __expf(2.f * si);
        float hp_ = (e2 - 1.f) / (e2 + 1.f);
        float hn = (1.f - zv[c]) * hold[c] + zv[c] * hp_;
        hold[c] = hn; hn4[c] = hn;
        packed[c >> 1] |= ((uint32_t)(uint16_t)f2bf(hn)) << ((c & 1) * 16);
      }
      atomic_store64(prodH, ((uint64_t)packed[1] << 32) | packed[0]);
      if (t == S_ - 1) {
#pragma unroll
        for (int c = 0; c < 4; ++c)
          out[((size_t)(m0 + row16) << 10) + (j << 4) + c4 + c] = hn4[c];
      }
      wait_vm0();                                     // release
      if (lane == 0) atomic_store32(fgrp + 1024 + (j << 4), (uint32_t)(t + 1));
#pragma unroll
      for (int c = 0; c < 4; ++c) { gz[c] = gzn[c]; gr[c] = grn[c]; gi[c] = gin[c]; }
    }
  }
}

// ---------------- launch ----------------

extern "C" void kernel_launch(void* const* d_in, const int* in_sizes, int n_in,
                              void* d_out, int out_size, void* d_ws, size_t ws_size,
                              hipStream_t stream) {
  const float* x  = (const float*)d_in[0];
  const float* Wm = (const float*)d_in[1];
  const float* bm = (const float*)d_in[2];
  const float* Wh = (const float*)d_in[3];
  const float* bh = (const float*)d_in[4];
  const float* Wz = (const float*)d_in[5];
  const float* bz = (const float*)d_in[6];
  const float* Wr = (const float*)d_in[7];
  const float* br = (const float*)d_in[8];
  const float* Wi = (const float*)d_in[9];
  const float* bi = (const float*)d_in[10];

  char* ws = (char*)d_ws;
  size_t off = 0;
  auto alloc = [&](size_t bytes) -> void* {
    void* p = ws + off; off += (bytes + 255) & ~(size_t)255; return p;
  };
  short* xbf   = (short*)alloc((size_t)B_ * S_ * D_ * 2);
  short* Gcat  = (short*)alloc((size_t)B_ * S_ * 3072 * 2);
  short* Mcat  = (short*)alloc((size_t)3072 * 768 * 2);
  short* Wcat  = (short*)alloc((size_t)3072 * 1024 * 2);
  short* WmT   = (short*)alloc((size_t)768 * 1024 * 2);
  short* Whbf  = (short*)alloc((size_t)1024 * 768 * 2);
  short* pk    = (short*)alloc((size_t)3 * 1024 * 1024 * 2);   // packed r,z,i frags
  float* ccat  = (float*)alloc(3072 * 4);
  float* hf    = (float*)alloc(65536 * 4);
  short* hp    = (short*)alloc(65536 * 2);                     // packed h exchange
  short* rhp   = (short*)alloc(65536 * 2);                     // packed r*h exchange
  uint32_t* flags = (uint32_t*)alloc((size_t)4 * 2048 * 4);    // line-padded flags
  if (off > ws_size) return;

  hipMemsetAsync(flags, 0, (size_t)4 * 2048 * 4, stream);
  cast_f32_bf16_kernel<<<2048, 256, 0, stream>>>(x, xbf, (B_ * S_ * D_) / 8);
  cast_f32_bf16_kernel<<<384, 256, 0, stream>>>(Wh, Whbf, (1024 * 768) / 8);
  build_wcat_kernel<<<1536, 256, 0, stream>>>(Wz, Wr, Wi, Wcat);
  transpose_cast_kernel<<<dim3(24, 32), dim3(32, 8), 0, stream>>>(Wm, WmT);
  ccat_kernel<<<768, 256, 0, stream>>>(Wz, Wr, Wi, bm, bz, br, bi, ccat);
  pack_w_kernel<<<1536, 256, 0, stream>>>(Wz, Wr, Wi, pk);

  // Mcat[3072,768] = Wcat[3072,1024] @ WmT[768,1024]^T
  gemm_nt_kernel<false><<<dim3(24, 6), 256, 0, stream>>>(Wcat, 1024, WmT, Mcat, 768,
                                                         nullptr, 3072, 768, 1024);
  // Gcat[32768,3072] = xbf[32768,768] @ Mcat[3072,768]^T + ccat
  gemm_nt_kernel<false><<<dim3(256, 24), 256, 0, stream>>>(xbf, 768, Mcat, Gcat, 3072,
                                                           ccat, 32768, 3072, 768);
  // hf[64,1024] = x[:,0,:] @ Whbf[1024,768]^T + bh
  gemm_nt_kernel<true><<<dim3(1, 8), 256, 0, stream>>>(xbf, (long)S_ * D_, Whbf, hf, 1024,
                                                       bh, 64, 1024, 768);
  pack_h0_kernel<<<256, 256, 0, stream>>>(hf, hp);

  recurrence_kernel<<<256, 256, 0, stream>>>(pk, Gcat, hf, hp, rhp, flags,
                                             (float*)d_out);
}